// Round 9
// baseline (21883.769 us; speedup 1.0000x reference)
//
#include <hip/hip_runtime.h>
#include <math.h>

// Problem constants (fixed by reference: x (9,256,32,32) fp32, att (9,32,32) fp32)
#define MR 1024      // m = 32*32 query locations
#define NC 8192      // n = 8*32*32 target locations
#define NCH 256      // channels
#define OT_ITERS 1000
#define IMG_STRIDE 262144  // 256*1024 floats per image
#define PBLK 256           // persistent grid: 1 block/CU, 512 threads
#define L2EF 1.44269504088896340736f
#define LN2F 0.69314718055994530942f

__device__ inline float wredMax(float v){
#pragma unroll
  for (int m = 32; m >= 1; m >>= 1) v = fmaxf(v, __shfl_xor(v, m, 64));
  return v;
}
__device__ inline float wredMin(float v){
#pragma unroll
  for (int m = 32; m >= 1; m >>= 1) v = fminf(v, __shfl_xor(v, m, 64));
  return v;
}
__device__ inline float wredSum(float v){
#pragma unroll
  for (int m = 32; m >= 1; m >>= 1) v += __shfl_xor(v, m, 64);
  return v;
}
__device__ inline int wredMinI(int v){
#pragma unroll
  for (int m = 32; m >= 1; m >>= 1) v = min(v, __shfl_xor(v, m, 64));
  return v;
}

__device__ inline unsigned fkey(float f){
  unsigned b = __float_as_uint(f);
  return (b & 0x80000000u) ? ~b : (b | 0x80000000u);
}
__device__ inline float funkey(unsigned k){
  return (k & 0x80000000u) ? __uint_as_float(k & 0x7fffffffu) : __uint_as_float(~k);
}

// coherent (bypass local caches) vector loads — for u/v/barrier-slot reads only
__device__ inline float4 cload_f4(const float4* p){
  float4 r;
  asm volatile("global_load_dwordx4 %0, %1, off sc0 sc1\n\ts_waitcnt vmcnt(0)"
               : "=v"(r) : "v"(p) : "memory");
  return r;
}
__device__ inline void cload_f4x4(float4* r, const float4* p){
  asm volatile(
    "global_load_dwordx4 %0, %4, off sc0 sc1\n\t"
    "global_load_dwordx4 %1, %5, off sc0 sc1\n\t"
    "global_load_dwordx4 %2, %6, off sc0 sc1\n\t"
    "global_load_dwordx4 %3, %7, off sc0 sc1\n\t"
    "s_waitcnt vmcnt(0)"
    : "=&v"(r[0]), "=&v"(r[1]), "=&v"(r[2]), "=v"(r[3])
    : "v"(p), "v"(p + 1), "v"(p + 2), "v"(p + 3)
    : "memory");
}
__device__ inline void astore(float* p, float val){
  __hip_atomic_store(p, val, __ATOMIC_RELAXED, __HIP_MEMORY_SCOPE_AGENT);
}

// K1: squared norms, log marginals, zero-init u,v,acc, minmax keys, barrier slots
__global__ __launch_bounds__(256) void kPrep(const float* __restrict__ x,
                                             const float* __restrict__ att,
                                             float* __restrict__ qq, float* __restrict__ tt,
                                             float* __restrict__ logmu, float* __restrict__ lognu,
                                             float* __restrict__ u, float* __restrict__ v,
                                             float* __restrict__ acc, unsigned* __restrict__ prmI,
                                             int* __restrict__ bar){
  int idx = blockIdx.x * 256 + threadIdx.x;
  if (idx < 9216){
    int img = idx >> 10, pos = idx & 1023;
    const float* p = x + img * IMG_STRIDE + pos;
    float s = 0.f;
#pragma unroll 8
    for (int c = 0; c < NCH; ++c){ float a = p[c * 1024]; s += a * a; }
    float lg = logf(att[idx]);
    if (img == 0){ qq[idx] = s;        logmu[idx] = lg; }
    else         { tt[idx - 1024] = s; lognu[idx - 1024] = lg; }
  }
  if (idx < MR) u[idx] = 0.f;
  if (idx < NC) v[idx] = 0.f;
  if (idx < 1024) bar[idx] = 0;
  if (idx == 0){ *acc = 0.f; prmI[0] = 0xFFFFFFFFu; prmI[1] = 0u; }
}

// K2: M[i][j] = qq[i] + tt[j] - 2 * Q_i . T_j ; also global min/max via key atomics
__global__ __launch_bounds__(256) void kGemmM(const float* __restrict__ x,
                                              const float* __restrict__ qq,
                                              const float* __restrict__ tt,
                                              float* __restrict__ M,
                                              unsigned* __restrict__ prmI){
  __shared__ float As[16][68];
  __shared__ float Bs[16][68];
  __shared__ float smn[4], smx[4];
  int jb = blockIdx.x;
  int ib = blockIdx.y;
  int i0 = ib * 64;
  int j0 = jb * 64;
  int k  = j0 >> 10, p0 = j0 & 1023;
  const float* A = x + i0;
  const float* B = x + (1 + k) * IMG_STRIDE + p0;
  int tid = threadIdx.x;
  int lr = tid >> 4, lc = (tid & 15) * 4;
  int ty = tid >> 4, tx = tid & 15;
  float accv[4][4] = {};
  for (int kt = 0; kt < 16; ++kt){
    int c = kt * 16 + lr;
    float4 av = *(const float4*)(A + c * 1024 + lc);
    float4 bv = *(const float4*)(B + c * 1024 + lc);
    *(float4*)(&As[lr][lc]) = av;
    *(float4*)(&Bs[lr][lc]) = bv;
    __syncthreads();
#pragma unroll
    for (int kk = 0; kk < 16; ++kk){
      float4 a = *(const float4*)(&As[kk][ty * 4]);
      float4 b = *(const float4*)(&Bs[kk][tx * 4]);
      float ar[4] = {a.x, a.y, a.z, a.w};
      float br[4] = {b.x, b.y, b.z, b.w};
#pragma unroll
      for (int r = 0; r < 4; ++r)
#pragma unroll
        for (int cc = 0; cc < 4; ++cc) accv[r][cc] += ar[r] * br[cc];
    }
    __syncthreads();
  }
  float tmn = INFINITY, tmx = -INFINITY;
#pragma unroll
  for (int r = 0; r < 4; ++r){
    int i = i0 + ty * 4 + r;
    float qi = qq[i];
    float o[4];
#pragma unroll
    for (int cc = 0; cc < 4; ++cc){
      o[cc] = qi + tt[j0 + tx * 4 + cc] - 2.f * accv[r][cc];
      tmn = fminf(tmn, o[cc]); tmx = fmaxf(tmx, o[cc]);
    }
    float4 ov = { o[0], o[1], o[2], o[3] };
    *(float4*)(M + (long)i * NC + j0 + tx * 4) = ov;
  }
  int lane = tid & 63, w = tid >> 6;
  tmn = wredMin(tmn); tmx = wredMax(tmx);
  if (lane == 0){ smn[w] = tmn; smx[w] = tmx; }
  __syncthreads();
  if (tid == 0){
    float bmn = fminf(fminf(smn[0], smn[1]), fminf(smn[2], smn[3]));
    float bmx = fmaxf(fmaxf(smx[0], smx[1]), fmaxf(smx[2], smx[3]));
    atomicMin(&prmI[0], fkey(bmn));
    atomicMax(&prmI[1], fkey(bmx));
  }
}

// K2b: one pass over M -> Mq (u16 row-major) + Mtq (u16 transposed); writes prm scale
__global__ __launch_bounds__(256) void kQuantTrans(const float* __restrict__ M,
                                                   unsigned short* __restrict__ Mq,
                                                   unsigned short* __restrict__ Mtq,
                                                   float* __restrict__ prm){
  __shared__ float tile[64][65];
  const unsigned* prmI = (const unsigned*)prm;
  float mn = funkey(prmI[0]);
  float mx = funkey(prmI[1]);
  float rng = mx - mn;
  float inv = (rng > 0.f) ? 65535.0f / rng : 0.f;
  float sc  = (rng > 0.f) ? rng / 65535.0f : 0.f;
  int i0 = blockIdx.y * 64;
  int j0 = blockIdx.x * 64;
  int t = threadIdx.x;
  int tc = t & 63, tr = t >> 6;
#pragma unroll
  for (int rr = 0; rr < 64; rr += 4)
    tile[rr + tr][tc] = M[(long)(i0 + rr + tr) * NC + j0 + tc];
  __syncthreads();
#pragma unroll
  for (int rr = 0; rr < 64; rr += 4){
    float a = tile[rr + tr][tc];
    int qa = (int)lrintf((a - mn) * inv);
    qa = qa < 0 ? 0 : (qa > 65535 ? 65535 : qa);
    Mq[(long)(i0 + rr + tr) * NC + j0 + tc] = (unsigned short)qa;
    float b = tile[tc][rr + tr];
    int qb = (int)lrintf((b - mn) * inv);
    qb = qb < 0 ? 0 : (qb > 65535 ? 65535 : qb);
    Mtq[(long)(j0 + rr + tr) * MR + i0 + tc] = (unsigned short)qb;
  }
  if (blockIdx.x == 0 && blockIdx.y == 0 && t == 0){ prm[2] = mn; prm[3] = sc; }
}

// store/poll epoch barrier: 256 slots, zero RMWs.
// Arrival: plain agent store of epoch to own slot (after vmcnt drain).
// Detection: wave 0 polls all 256 slots with ONE dwordx4 coherent load per lane
// + wave-min; exits when min >= ep. No release chain, no atomic serialization.
__device__ inline void gbar2(int* slots, int b, int ep){
  __syncthreads();
  if (threadIdx.x < 64){
    int lane = threadIdx.x;
    if (lane == 0){
      asm volatile("s_waitcnt vmcnt(0)" ::: "memory");  // data stores drained
      __hip_atomic_store(&slots[b], ep, __ATOMIC_RELAXED, __HIP_MEMORY_SCOPE_AGENT);
    }
    const float4* p = (const float4*)slots + lane;  // lane covers slots[4l..4l+3]
    for (;;){
      float4 s4 = cload_f4(p);
      int m0 = min(min(__float_as_int(s4.x), __float_as_int(s4.y)),
                   min(__float_as_int(s4.z), __float_as_int(s4.w)));
      if (wredMinI(m0) >= ep) break;
      __builtin_amdgcn_s_sleep(2);
    }
  }
  __syncthreads();
}

// persistent dense Sinkhorn: 256 blocks x 512 thr; block owns 4 u-rows + 32 v-cols.
// R4-proven two-pass LSE math in exp2 domain; u16 matrix reads stay L2-local;
// u/v exchanged via coherent loads staged once per phase into LDS.
__global__ __launch_bounds__(512) void kSink5(const unsigned short* __restrict__ Mq,
                                              const unsigned short* __restrict__ Mtq,
                                              const float* __restrict__ logmu,
                                              const float* __restrict__ lognu,
                                              float* __restrict__ u,
                                              float* __restrict__ v,
                                              const float* __restrict__ prm,
                                              int* __restrict__ bar){
  __shared__ float vsh[8192];   // 32 KB: L2EF * v
  __shared__ float ush[1024];   // 4 KB: L2EF * u
  __shared__ float redA[8], redB[8];
  int tid = threadIdx.x, b = blockIdx.x;
  int lane = tid & 63, w = tid >> 6;
  float mn = prm[2], s = prm[3];
  float s2 = s * L2EF;
  int r0 = 4 * b;
  int jb0 = 32 * b + 4 * w;     // this wave's first column
  float lmu[4];
#pragma unroll
  for (int r = 0; r < 4; ++r) lmu[r] = logmu[r0 + r];
  float lnu4[4];
#pragma unroll
  for (int cc = 0; cc < 4; ++cc) lnu4[cc] = lognu[jb0 + cc];
  int ep = 0;

  for (int it = 0; it < OT_ITERS; ++it){
    // ---- stage v (coherent, batched dwordx4) -> LDS, scaled to log2 domain ----
    {
      float4 vb[4];
      cload_f4x4(vb, (const float4*)v + 4 * tid);
      float4* d = (float4*)&vsh[16 * tid];
#pragma unroll
      for (int k = 0; k < 4; ++k){
        vb[k].x *= L2EF; vb[k].y *= L2EF; vb[k].z *= L2EF; vb[k].w *= L2EF;
        d[k] = vb[k];
      }
    }
    __syncthreads();

    // ---- u-pass: 4 rows, all 512 threads per row; thread owns elems 16t..16t+15 ----
#pragma unroll
    for (int r = 0; r < 4; ++r){
      const unsigned short* Rr = Mq + (long)(r0 + r) * NC + 16 * tid;
      uint4 qa = *(const uint4*)(Rr);
      uint4 qb = *(const uint4*)(Rr + 8);
      const float* vp = &vsh[16 * tid];
      float4 v0 = *(const float4*)(vp);
      float4 v1 = *(const float4*)(vp + 4);
      float4 v2 = *(const float4*)(vp + 8);
      float4 v3 = *(const float4*)(vp + 12);
      float tv[16];
      tv[0]  = fmaf(s2, (float)(qa.x & 0xFFFFu), v0.x);
      tv[1]  = fmaf(s2, (float)(qa.x >> 16),     v0.y);
      tv[2]  = fmaf(s2, (float)(qa.y & 0xFFFFu), v0.z);
      tv[3]  = fmaf(s2, (float)(qa.y >> 16),     v0.w);
      tv[4]  = fmaf(s2, (float)(qa.z & 0xFFFFu), v1.x);
      tv[5]  = fmaf(s2, (float)(qa.z >> 16),     v1.y);
      tv[6]  = fmaf(s2, (float)(qa.w & 0xFFFFu), v1.z);
      tv[7]  = fmaf(s2, (float)(qa.w >> 16),     v1.w);
      tv[8]  = fmaf(s2, (float)(qb.x & 0xFFFFu), v2.x);
      tv[9]  = fmaf(s2, (float)(qb.x >> 16),     v2.y);
      tv[10] = fmaf(s2, (float)(qb.y & 0xFFFFu), v2.z);
      tv[11] = fmaf(s2, (float)(qb.y >> 16),     v2.w);
      tv[12] = fmaf(s2, (float)(qb.z & 0xFFFFu), v3.x);
      tv[13] = fmaf(s2, (float)(qb.z >> 16),     v3.y);
      tv[14] = fmaf(s2, (float)(qb.w & 0xFFFFu), v3.z);
      tv[15] = fmaf(s2, (float)(qb.w >> 16),     v3.w);
      float mx = -INFINITY;
#pragma unroll
      for (int q = 0; q < 16; ++q) mx = fmaxf(mx, tv[q]);
      mx = wredMax(mx);
      if (lane == 0) redA[w] = mx;
      __syncthreads();
      float bmx = fmaxf(fmaxf(fmaxf(redA[0], redA[1]), fmaxf(redA[2], redA[3])),
                        fmaxf(fmaxf(redA[4], redA[5]), fmaxf(redA[6], redA[7])));
      float sm = 0.f;
#pragma unroll
      for (int q = 0; q < 16; ++q) sm += __builtin_exp2f(tv[q] - bmx);
      sm = wredSum(sm);
      if (lane == 0) redB[w] = sm;
      __syncthreads();
      if (tid == 0){
        float tot = ((redB[0] + redB[1]) + (redB[2] + redB[3]))
                  + ((redB[4] + redB[5]) + (redB[6] + redB[7]));
        astore(u + r0 + r, lmu[r] - mn - (bmx + __builtin_log2f(tot)) * LN2F);
      }
      __syncthreads();
    }
    gbar2(bar, b, ++ep);   // u complete everywhere

    // ---- stage u (coherent) -> LDS, scaled ----
    if (tid < 256){
      float4 uu = cload_f4((const float4*)u + tid);
      uu.x *= L2EF; uu.y *= L2EF; uu.z *= L2EF; uu.w *= L2EF;
      *(float4*)&ush[4 * tid] = uu;
    }
    __syncthreads();

    // ---- v-pass: 4 cols per wave, wave-local reductions; lane owns elems 16l..16l+15 ----
#pragma unroll
    for (int cc = 0; cc < 4; ++cc){
      int j = jb0 + cc;
      const unsigned short* Rc = Mtq + (long)j * MR + 16 * lane;
      uint4 qa = *(const uint4*)(Rc);
      uint4 qb = *(const uint4*)(Rc + 8);
      const float* up = &ush[16 * lane];
      float4 u0 = *(const float4*)(up);
      float4 u1 = *(const float4*)(up + 4);
      float4 u2 = *(const float4*)(up + 8);
      float4 u3 = *(const float4*)(up + 12);
      float tv[16];
      tv[0]  = fmaf(s2, (float)(qa.x & 0xFFFFu), u0.x);
      tv[1]  = fmaf(s2, (float)(qa.x >> 16),     u0.y);
      tv[2]  = fmaf(s2, (float)(qa.y & 0xFFFFu), u0.z);
      tv[3]  = fmaf(s2, (float)(qa.y >> 16),     u0.w);
      tv[4]  = fmaf(s2, (float)(qa.z & 0xFFFFu), u1.x);
      tv[5]  = fmaf(s2, (float)(qa.z >> 16),     u1.y);
      tv[6]  = fmaf(s2, (float)(qa.w & 0xFFFFu), u1.z);
      tv[7]  = fmaf(s2, (float)(qa.w >> 16),     u1.w);
      tv[8]  = fmaf(s2, (float)(qb.x & 0xFFFFu), u2.x);
      tv[9]  = fmaf(s2, (float)(qb.x >> 16),     u2.y);
      tv[10] = fmaf(s2, (float)(qb.y & 0xFFFFu), u2.z);
      tv[11] = fmaf(s2, (float)(qb.y >> 16),     u2.w);
      tv[12] = fmaf(s2, (float)(qb.z & 0xFFFFu), u3.x);
      tv[13] = fmaf(s2, (float)(qb.z >> 16),     u3.y);
      tv[14] = fmaf(s2, (float)(qb.w & 0xFFFFu), u3.z);
      tv[15] = fmaf(s2, (float)(qb.w >> 16),     u3.w);
      float mx = -INFINITY;
#pragma unroll
      for (int q = 0; q < 16; ++q) mx = fmaxf(mx, tv[q]);
      mx = wredMax(mx);
      float sm = 0.f;
#pragma unroll
      for (int q = 0; q < 16; ++q) sm += __builtin_exp2f(tv[q] - mx);
      sm = wredSum(sm);
      if (lane == 0) astore(v + j, lnu4[cc] - mn - (mx + __builtin_log2f(sm)) * LN2F);
    }
    gbar2(bar, b, ++ep);   // v complete everywhere
  }
}

// fallback (R4 path): used only if cooperative launch fails
__global__ __launch_bounds__(256) void kUPassQ(const unsigned short* __restrict__ Mq,
                                               const float* __restrict__ v,
                                               const float* __restrict__ logmu,
                                               float* __restrict__ u,
                                               const float* __restrict__ prm){
  int b = blockIdx.x, tid = threadIdx.x;
  float mn = prm[2], s = prm[3];
  int r0 = 2 * b;
  const unsigned short* R0 = Mq + (long)r0 * NC;
  const unsigned short* R1 = R0 + NC;
  float t0[32], t1[32];
  float mx0 = -INFINITY, mx1 = -INFINITY;
#pragma unroll
  for (int kb = 0; kb < 4; ++kb){
    int cidx = kb * 2048 + tid * 8;
    uint4 qa = *(const uint4*)(R0 + cidx);
    uint4 qb = *(const uint4*)(R1 + cidx);
    float4 v0 = *(const float4*)(v + cidx);
    float4 v1 = *(const float4*)(v + cidx + 4);
    float a0 = fmaf(s, (float)(qa.x & 0xFFFFu), v0.x);
    float a1 = fmaf(s, (float)(qa.x >> 16),     v0.y);
    float a2 = fmaf(s, (float)(qa.y & 0xFFFFu), v0.z);
    float a3 = fmaf(s, (float)(qa.y >> 16),     v0.w);
    float a4 = fmaf(s, (float)(qa.z & 0xFFFFu), v1.x);
    float a5 = fmaf(s, (float)(qa.z >> 16),     v1.y);
    float a6 = fmaf(s, (float)(qa.w & 0xFFFFu), v1.z);
    float a7 = fmaf(s, (float)(qa.w >> 16),     v1.w);
    float c0 = fmaf(s, (float)(qb.x & 0xFFFFu), v0.x);
    float c1 = fmaf(s, (float)(qb.x >> 16),     v0.y);
    float c2 = fmaf(s, (float)(qb.y & 0xFFFFu), v0.z);
    float c3 = fmaf(s, (float)(qb.y >> 16),     v0.w);
    float c4 = fmaf(s, (float)(qb.z & 0xFFFFu), v1.x);
    float c5 = fmaf(s, (float)(qb.z >> 16),     v1.y);
    float c6 = fmaf(s, (float)(qb.w & 0xFFFFu), v1.z);
    float c7 = fmaf(s, (float)(qb.w >> 16),     v1.w);
    t0[kb*8+0]=a0; t0[kb*8+1]=a1; t0[kb*8+2]=a2; t0[kb*8+3]=a3;
    t0[kb*8+4]=a4; t0[kb*8+5]=a5; t0[kb*8+6]=a6; t0[kb*8+7]=a7;
    t1[kb*8+0]=c0; t1[kb*8+1]=c1; t1[kb*8+2]=c2; t1[kb*8+3]=c3;
    t1[kb*8+4]=c4; t1[kb*8+5]=c5; t1[kb*8+6]=c6; t1[kb*8+7]=c7;
    mx0 = fmaxf(mx0, fmaxf(fmaxf(fmaxf(a0,a1),fmaxf(a2,a3)), fmaxf(fmaxf(a4,a5),fmaxf(a6,a7))));
    mx1 = fmaxf(mx1, fmaxf(fmaxf(fmaxf(c0,c1),fmaxf(c2,c3)), fmaxf(fmaxf(c4,c5),fmaxf(c6,c7))));
  }
  __shared__ float redA0[4], redA1[4], redB0[4], redB1[4];
  int lane = tid & 63, w = tid >> 6;
  float wm0 = wredMax(mx0), wm1 = wredMax(mx1);
  if (lane == 0){ redA0[w] = wm0; redA1[w] = wm1; }
  __syncthreads();
  float bm0 = fmaxf(fmaxf(redA0[0], redA0[1]), fmaxf(redA0[2], redA0[3]));
  float bm1 = fmaxf(fmaxf(redA1[0], redA1[1]), fmaxf(redA1[2], redA1[3]));
  float s0 = 0.f, s1 = 0.f;
#pragma unroll
  for (int q = 0; q < 32; ++q){ s0 += __expf(t0[q] - bm0); s1 += __expf(t1[q] - bm1); }
  s0 = wredSum(s0); s1 = wredSum(s1);
  if (lane == 0){ redB0[w] = s0; redB1[w] = s1; }
  __syncthreads();
  if (tid == 0){
    u[r0]     = logmu[r0]     - mn - (bm0 + __logf(redB0[0] + redB0[1] + redB0[2] + redB0[3]));
    u[r0 + 1] = logmu[r0 + 1] - mn - (bm1 + __logf(redB1[0] + redB1[1] + redB1[2] + redB1[3]));
  }
}

__global__ __launch_bounds__(256) void kVPassQ(const unsigned short* __restrict__ Mtq,
                                               const float* __restrict__ u,
                                               const float* __restrict__ lognu,
                                               float* __restrict__ v,
                                               const float* __restrict__ prm){
  __shared__ float ulds[1024];
  int tid = threadIdx.x;
  float mn = prm[2], s = prm[3];
  *(float4*)(&ulds[tid * 4]) = *(const float4*)(u + tid * 4);
  __syncthreads();
  int w = tid >> 6, lane = tid & 63;
#pragma unroll
  for (int cc = 0; cc < 4; ++cc){
    int j = blockIdx.x * 16 + w * 4 + cc;
    const unsigned short* R = Mtq + (long)j * MR;
    uint4 qa = *(const uint4*)(R + lane * 8);
    uint4 qb = *(const uint4*)(R + 512 + lane * 8);
    float4 ua0 = *(const float4*)(&ulds[lane * 8]);
    float4 ua1 = *(const float4*)(&ulds[lane * 8 + 4]);
    float4 ub0 = *(const float4*)(&ulds[512 + lane * 8]);
    float4 ub1 = *(const float4*)(&ulds[512 + lane * 8 + 4]);
    float tv[16];
    tv[0]  = fmaf(s, (float)(qa.x & 0xFFFFu), ua0.x);
    tv[1]  = fmaf(s, (float)(qa.x >> 16),     ua0.y);
    tv[2]  = fmaf(s, (float)(qa.y & 0xFFFFu), ua0.z);
    tv[3]  = fmaf(s, (float)(qa.y >> 16),     ua0.w);
    tv[4]  = fmaf(s, (float)(qa.z & 0xFFFFu), ua1.x);
    tv[5]  = fmaf(s, (float)(qa.z >> 16),     ua1.y);
    tv[6]  = fmaf(s, (float)(qa.w & 0xFFFFu), ua1.z);
    tv[7]  = fmaf(s, (float)(qa.w >> 16),     ua1.w);
    tv[8]  = fmaf(s, (float)(qb.x & 0xFFFFu), ub0.x);
    tv[9]  = fmaf(s, (float)(qb.x >> 16),     ub0.y);
    tv[10] = fmaf(s, (float)(qb.y & 0xFFFFu), ub0.z);
    tv[11] = fmaf(s, (float)(qb.y >> 16),     ub0.w);
    tv[12] = fmaf(s, (float)(qb.z & 0xFFFFu), ub1.x);
    tv[13] = fmaf(s, (float)(qb.z >> 16),     ub1.y);
    tv[14] = fmaf(s, (float)(qb.w & 0xFFFFu), ub1.z);
    tv[15] = fmaf(s, (float)(qb.w >> 16),     ub1.w);
    float mx = -INFINITY;
#pragma unroll
    for (int q = 0; q < 16; ++q) mx = fmaxf(mx, tv[q]);
    mx = wredMax(mx);
    float sm = 0.f;
#pragma unroll
    for (int q = 0; q < 16; ++q) sm += __expf(tv[q] - mx);
    sm = wredSum(sm);
    if (lane == 0) v[j] = lognu[j] - mn - (mx + __logf(sm));
  }
}

// K5: o = P@T rows, diff = mu*Q - o, acc += sum_i ||diff_i||_2 ; 4 rows per block
__global__ __launch_bounds__(256) void kFinal(const float* __restrict__ x,
                                              const float* __restrict__ att,
                                              const float* __restrict__ M,
                                              const float* __restrict__ u,
                                              const float* __restrict__ v,
                                              float* __restrict__ acc){
  __shared__ float pch[4][256];
  __shared__ float redS[4];
  int tid = threadIdx.x;
  int r0 = blockIdx.x * 4;
  float u4[4];
#pragma unroll
  for (int rr = 0; rr < 4; ++rr) u4[rr] = u[r0 + rr];
  float o[4] = {0.f, 0.f, 0.f, 0.f};
  for (int jc = 0; jc < NC; jc += 256){
    float vv = v[jc + tid];
#pragma unroll
    for (int rr = 0; rr < 4; ++rr)
      pch[rr][tid] = __expf(M[(long)(r0 + rr) * NC + jc + tid] + u4[rr] + vv);
    __syncthreads();
    int k = jc >> 10;
    const float* Tp = x + (1 + k) * IMG_STRIDE + tid * 1024 + (jc & 1023);
    for (int jj = 0; jj < 256; jj += 4){
      float4 tv = *(const float4*)(Tp + jj);
      float tq[4] = {tv.x, tv.y, tv.z, tv.w};
#pragma unroll
      for (int q = 0; q < 4; ++q){
        o[0] += pch[0][jj + q] * tq[q];
        o[1] += pch[1][jj + q] * tq[q];
        o[2] += pch[2][jj + q] * tq[q];
        o[3] += pch[3][jj + q] * tq[q];
      }
    }
    __syncthreads();
  }
  int lane = tid & 63, wid = tid >> 6;
  float dtot = 0.f;
#pragma unroll
  for (int rr = 0; rr < 4; ++rr){
    float mu = att[r0 + rr];
    float qv = x[tid * 1024 + (r0 + rr)];
    float diff = mu * qv - o[rr];
    float wsum = wredSum(diff * diff);
    if (lane == 0) redS[wid] = wsum;
    __syncthreads();
    if (tid == 0) dtot += sqrtf(redS[0] + redS[1] + redS[2] + redS[3]);
    __syncthreads();
  }
  if (tid == 0) atomicAdd(acc, dtot);
}

// K6: apply label/margin, write scalar output
__global__ void kOut(const float* __restrict__ acc, const int* __restrict__ label,
                     float* __restrict__ out){
  if (threadIdx.x == 0 && blockIdx.x == 0){
    float d = *acc;
    out[0] = (*label) ? d : fmaxf(0.7f - d, 0.f);
  }
}

extern "C" void kernel_launch(void* const* d_in, const int* in_sizes, int n_in,
                              void* d_out, int out_size, void* d_ws, size_t ws_size,
                              hipStream_t stream){
  const float* x   = (const float*)d_in[0];
  const float* att = (const float*)d_in[1];
  const int* label = (const int*)d_in[2];
  float* W = (float*)d_ws;
  float* out = (float*)d_out;

  float* M = W;                                                   // 32 MB
  unsigned short* Mq  = (unsigned short*)(W + 8388608);           // 16 MB
  unsigned short* Mtq = (unsigned short*)(W + 8388608 + 4194304); // 16 MB
  float* S     = W + 16777216;
  float* qq    = S;                  // 1024
  float* tt    = S + 1024;           // 8192
  float* logmu = S + 9216;           // 1024
  float* lognu = S + 10240;          // 8192
  float* u     = S + 18432;          // 1024  (16B aligned)
  float* v     = S + 19456;          // 8192  (16B aligned)
  float* acc   = S + 27648;          // 1
  float* prm   = S + 27652;          // 4: [0]=min key, [1]=max key, [2]=mn, [3]=scale
  unsigned* prmI = (unsigned*)prm;
  int*   bar   = (int*)(S + 27664);  // 1024 ints, 16B aligned (slots 0..255 used)

  hipLaunchKernelGGL(kPrep, dim3(37), dim3(256), 0, stream, x, att, qq, tt, logmu, lognu, u, v, acc, prmI, bar);
  hipLaunchKernelGGL(kGemmM, dim3(128, 16), dim3(256), 0, stream, x, qq, tt, M, prmI);
  hipLaunchKernelGGL(kQuantTrans, dim3(128, 16), dim3(256), 0, stream, M, Mq, Mtq, prm);

  void* args[] = { (void*)&Mq, (void*)&Mtq, (void*)&logmu, (void*)&lognu,
                   (void*)&u, (void*)&v, (void*)&prm, (void*)&bar };
  hipError_t rc = hipLaunchCooperativeKernel((const void*)kSink5,
                                             dim3(PBLK), dim3(512), args, 0, stream);
  if (rc != hipSuccess){
    for (int it = 0; it < OT_ITERS; ++it){
      hipLaunchKernelGGL(kUPassQ, dim3(512), dim3(256), 0, stream, Mq, v, logmu, u, prm);
      hipLaunchKernelGGL(kVPassQ, dim3(512), dim3(256), 0, stream, Mtq, u, lognu, v, prm);
    }
  }
  hipLaunchKernelGGL(kFinal, dim3(256), dim3(256), 0, stream, x, att, M, u, v, acc);
  hipLaunchKernelGGL(kOut, dim3(1), dim3(1), 0, stream, acc, label, out);
}

// Round 10
// 16549.664 us; speedup vs baseline: 1.3223x; 1.3223x over previous
//
#include <hip/hip_runtime.h>
#include <math.h>

// Problem constants (fixed by reference: x (9,256,32,32) fp32, att (9,32,32) fp32)
#define MR 1024      // m = 32*32 query locations
#define NC 8192      // n = 8*32*32 target locations
#define NCH 256      // channels
#define OT_ITERS 1000
#define IMG_STRIDE 262144  // 256*1024 floats per image
#define PBLK 256           // persistent grid: 1 block/CU, 512 threads
#define L2EF 1.44269504088896340736f
#define LN2F 0.69314718055994530942f

__device__ inline float wredMax(float v){
#pragma unroll
  for (int m = 32; m >= 1; m >>= 1) v = fmaxf(v, __shfl_xor(v, m, 64));
  return v;
}
__device__ inline float wredMin(float v){
#pragma unroll
  for (int m = 32; m >= 1; m >>= 1) v = fminf(v, __shfl_xor(v, m, 64));
  return v;
}
__device__ inline float wredSum(float v){
#pragma unroll
  for (int m = 32; m >= 1; m >>= 1) v += __shfl_xor(v, m, 64);
  return v;
}
__device__ inline int wredMinI(int v){
#pragma unroll
  for (int m = 32; m >= 1; m >>= 1) v = min(v, __shfl_xor(v, m, 64));
  return v;
}

__device__ inline unsigned fkey(float f){
  unsigned b = __float_as_uint(f);
  return (b & 0x80000000u) ? ~b : (b | 0x80000000u);
}
__device__ inline float funkey(unsigned k){
  return (k & 0x80000000u) ? __uint_as_float(k & 0x7fffffffu) : __uint_as_float(~k);
}

// agent-scope (device-coherent) scalar load/store for u/v + barrier exchange
__device__ inline float aload(const float* p){
  return __hip_atomic_load(p, __ATOMIC_RELAXED, __HIP_MEMORY_SCOPE_AGENT);
}
__device__ inline int aloadI(const int* p){
  return __hip_atomic_load(p, __ATOMIC_RELAXED, __HIP_MEMORY_SCOPE_AGENT);
}
__device__ inline void astore(float* p, float val){
  __hip_atomic_store(p, val, __ATOMIC_RELAXED, __HIP_MEMORY_SCOPE_AGENT);
}
__device__ inline void astoreI(int* p, int val){
  __hip_atomic_store(p, val, __ATOMIC_RELAXED, __HIP_MEMORY_SCOPE_AGENT);
}
// coherent 16B load (aggregator slot polling only)
__device__ inline float4 cload_f4(const float4* p){
  float4 r;
  asm volatile("global_load_dwordx4 %0, %1, off sc0 sc1\n\ts_waitcnt vmcnt(0)"
               : "=v"(r) : "v"(p) : "memory");
  return r;
}

// K1: squared norms, log marginals, zero-init u,v,acc, minmax keys, barrier slots
__global__ __launch_bounds__(256) void kPrep(const float* __restrict__ x,
                                             const float* __restrict__ att,
                                             float* __restrict__ qq, float* __restrict__ tt,
                                             float* __restrict__ logmu, float* __restrict__ lognu,
                                             float* __restrict__ u, float* __restrict__ v,
                                             float* __restrict__ acc, unsigned* __restrict__ prmI,
                                             int* __restrict__ bar){
  int idx = blockIdx.x * 256 + threadIdx.x;
  if (idx < 9216){
    int img = idx >> 10, pos = idx & 1023;
    const float* p = x + img * IMG_STRIDE + pos;
    float s = 0.f;
#pragma unroll 8
    for (int c = 0; c < NCH; ++c){ float a = p[c * 1024]; s += a * a; }
    float lg = logf(att[idx]);
    if (img == 0){ qq[idx] = s;        logmu[idx] = lg; }
    else         { tt[idx - 1024] = s; lognu[idx - 1024] = lg; }
  }
  if (idx < MR) u[idx] = 0.f;
  if (idx < NC) v[idx] = 0.f;
  if (idx < 1024) bar[idx] = 0;
  if (idx == 0){ *acc = 0.f; prmI[0] = 0xFFFFFFFFu; prmI[1] = 0u; }
}

// K2: M[i][j] = qq[i] + tt[j] - 2 * Q_i . T_j ; also global min/max via key atomics
__global__ __launch_bounds__(256) void kGemmM(const float* __restrict__ x,
                                              const float* __restrict__ qq,
                                              const float* __restrict__ tt,
                                              float* __restrict__ M,
                                              unsigned* __restrict__ prmI){
  __shared__ float As[16][68];
  __shared__ float Bs[16][68];
  __shared__ float smn[4], smx[4];
  int jb = blockIdx.x;
  int ib = blockIdx.y;
  int i0 = ib * 64;
  int j0 = jb * 64;
  int k  = j0 >> 10, p0 = j0 & 1023;
  const float* A = x + i0;
  const float* B = x + (1 + k) * IMG_STRIDE + p0;
  int tid = threadIdx.x;
  int lr = tid >> 4, lc = (tid & 15) * 4;
  int ty = tid >> 4, tx = tid & 15;
  float accv[4][4] = {};
  for (int kt = 0; kt < 16; ++kt){
    int c = kt * 16 + lr;
    float4 av = *(const float4*)(A + c * 1024 + lc);
    float4 bv = *(const float4*)(B + c * 1024 + lc);
    *(float4*)(&As[lr][lc]) = av;
    *(float4*)(&Bs[lr][lc]) = bv;
    __syncthreads();
#pragma unroll
    for (int kk = 0; kk < 16; ++kk){
      float4 a = *(const float4*)(&As[kk][ty * 4]);
      float4 b = *(const float4*)(&Bs[kk][tx * 4]);
      float ar[4] = {a.x, a.y, a.z, a.w};
      float br[4] = {b.x, b.y, b.z, b.w};
#pragma unroll
      for (int r = 0; r < 4; ++r)
#pragma unroll
        for (int cc = 0; cc < 4; ++cc) accv[r][cc] += ar[r] * br[cc];
    }
    __syncthreads();
  }
  float tmn = INFINITY, tmx = -INFINITY;
#pragma unroll
  for (int r = 0; r < 4; ++r){
    int i = i0 + ty * 4 + r;
    float qi = qq[i];
    float o[4];
#pragma unroll
    for (int cc = 0; cc < 4; ++cc){
      o[cc] = qi + tt[j0 + tx * 4 + cc] - 2.f * accv[r][cc];
      tmn = fminf(tmn, o[cc]); tmx = fmaxf(tmx, o[cc]);
    }
    float4 ov = { o[0], o[1], o[2], o[3] };
    *(float4*)(M + (long)i * NC + j0 + tx * 4) = ov;
  }
  int lane = tid & 63, w = tid >> 6;
  tmn = wredMin(tmn); tmx = wredMax(tmx);
  if (lane == 0){ smn[w] = tmn; smx[w] = tmx; }
  __syncthreads();
  if (tid == 0){
    float bmn = fminf(fminf(smn[0], smn[1]), fminf(smn[2], smn[3]));
    float bmx = fmaxf(fmaxf(smx[0], smx[1]), fmaxf(smx[2], smx[3]));
    atomicMin(&prmI[0], fkey(bmn));
    atomicMax(&prmI[1], fkey(bmx));
  }
}

// K2b: one pass over M -> Mq (u16 row-major) + Mtq (u16 transposed); writes prm scale
__global__ __launch_bounds__(256) void kQuantTrans(const float* __restrict__ M,
                                                   unsigned short* __restrict__ Mq,
                                                   unsigned short* __restrict__ Mtq,
                                                   float* __restrict__ prm){
  __shared__ float tile[64][65];
  const unsigned* prmI = (const unsigned*)prm;
  float mn = funkey(prmI[0]);
  float mx = funkey(prmI[1]);
  float rng = mx - mn;
  float inv = (rng > 0.f) ? 65535.0f / rng : 0.f;
  float sc  = (rng > 0.f) ? rng / 65535.0f : 0.f;
  int i0 = blockIdx.y * 64;
  int j0 = blockIdx.x * 64;
  int t = threadIdx.x;
  int tc = t & 63, tr = t >> 6;
#pragma unroll
  for (int rr = 0; rr < 64; rr += 4)
    tile[rr + tr][tc] = M[(long)(i0 + rr + tr) * NC + j0 + tc];
  __syncthreads();
#pragma unroll
  for (int rr = 0; rr < 64; rr += 4){
    float a = tile[rr + tr][tc];
    int qa = (int)lrintf((a - mn) * inv);
    qa = qa < 0 ? 0 : (qa > 65535 ? 65535 : qa);
    Mq[(long)(i0 + rr + tr) * NC + j0 + tc] = (unsigned short)qa;
    float b = tile[tc][rr + tr];
    int qb = (int)lrintf((b - mn) * inv);
    qb = qb < 0 ? 0 : (qb > 65535 ? 65535 : qb);
    Mtq[(long)(j0 + rr + tr) * MR + i0 + tc] = (unsigned short)qb;
  }
  if (blockIdx.x == 0 && blockIdx.y == 0 && t == 0){ prm[2] = mn; prm[3] = sc; }
}

// aggregator epoch barrier, zero RMWs:
//  arrival:   every wave drains own stores (vmcnt), block stores ep to own slot
//  detection: block 0 wave 0 polls all 256 slots (one dwordx4/lane) -> wave-min
//  release:   block 0 lanes 0..7 store ep to 8 spread lines; others poll one line
__device__ inline void gbar3(int* slots, int* rel, int b, int g, int ep){
  asm volatile("s_waitcnt vmcnt(0)" ::: "memory");  // per-wave: own stores ACKed
  __syncthreads();
  if (b == 0){
    if (threadIdx.x < 64){
      if (threadIdx.x == 0) astoreI(&slots[0], ep);
      const float4* p = (const float4*)slots + threadIdx.x;
      for (;;){
        float4 s4 = cload_f4(p);
        int m0 = min(min(__float_as_int(s4.x), __float_as_int(s4.y)),
                     min(__float_as_int(s4.z), __float_as_int(s4.w)));
        if (wredMinI(m0) >= ep) break;
        __builtin_amdgcn_s_sleep(1);
      }
      if (threadIdx.x < 8) astoreI(&rel[threadIdx.x * 16], ep);
    }
  } else {
    if (threadIdx.x == 0){
      astoreI(&slots[b], ep);
      while (aloadI(&rel[g * 16]) < ep) __builtin_amdgcn_s_sleep(2);
    }
  }
  __syncthreads();
}

// persistent dense Sinkhorn: 256 blocks x 512 thr; block owns 4 u-rows + 32 v-cols.
// Stride-4 chunk ownership -> conflict-free LDS; exp2-domain two-pass LSE;
// u/v exchange via coalesced scalar agent loads staged into LDS.
__global__ __launch_bounds__(512) void kSink6(const unsigned short* __restrict__ Mq,
                                              const unsigned short* __restrict__ Mtq,
                                              const float* __restrict__ logmu,
                                              const float* __restrict__ lognu,
                                              float* __restrict__ u,
                                              float* __restrict__ v,
                                              const float* __restrict__ prm,
                                              int* __restrict__ bar){
  __shared__ float vsh[8192];   // 32 KB: L2EF * v
  __shared__ float ush[1024];   // 4 KB:  L2EF * u
  __shared__ float redA[8], redB[8];
  int tid = threadIdx.x, b = blockIdx.x;
  int lane = tid & 63, w = tid >> 6;
  int g = b & 7;
  float mn = prm[2], s = prm[3];
  float s2 = s * L2EF;
  int r0 = 4 * b;
  int jc0 = 32 * b + 4 * w;     // this wave's first column
  float lmu[4];
#pragma unroll
  for (int r = 0; r < 4; ++r) lmu[r] = logmu[r0 + r];
  float lnu4[4];
#pragma unroll
  for (int cc = 0; cc < 4; ++cc) lnu4[cc] = lognu[jc0 + cc];
  int* slots = bar;
  int* rel   = bar + 256;
  int ep = 0;

  for (int it = 0; it < OT_ITERS; ++it){
    // ---- stage v -> LDS (coalesced scalar agent loads), scaled to log2 domain ----
    {
      float tmp[16];
#pragma unroll
      for (int q = 0; q < 16; ++q) tmp[q] = aload(v + tid + 512 * q);
#pragma unroll
      for (int q = 0; q < 16; ++q) vsh[tid + 512 * q] = L2EF * tmp[q];
    }
    __syncthreads();

    // ---- u-pass: 4 rows sequential, 512 threads/row; thread owns 4-elem chunks ----
#pragma unroll
    for (int r = 0; r < 4; ++r){
      const unsigned short* Rr = Mq + (long)(r0 + r) * NC;
      float tv[16];
      float mx = -INFINITY;
#pragma unroll
      for (int k = 0; k < 4; ++k){
        int j = 4 * tid + 2048 * k;
        uint2 q2 = *(const uint2*)(Rr + j);
        float4 vv = *(const float4*)(&vsh[j]);
        float e0 = fmaf(s2, (float)(q2.x & 0xFFFFu), vv.x);
        float e1 = fmaf(s2, (float)(q2.x >> 16),     vv.y);
        float e2 = fmaf(s2, (float)(q2.y & 0xFFFFu), vv.z);
        float e3 = fmaf(s2, (float)(q2.y >> 16),     vv.w);
        tv[4*k+0] = e0; tv[4*k+1] = e1; tv[4*k+2] = e2; tv[4*k+3] = e3;
        mx = fmaxf(mx, fmaxf(fmaxf(e0, e1), fmaxf(e2, e3)));
      }
      mx = wredMax(mx);
      if (lane == 0) redA[w] = mx;
      __syncthreads();
      float bmx = fmaxf(fmaxf(fmaxf(redA[0], redA[1]), fmaxf(redA[2], redA[3])),
                        fmaxf(fmaxf(redA[4], redA[5]), fmaxf(redA[6], redA[7])));
      float sm = 0.f;
#pragma unroll
      for (int q = 0; q < 16; ++q) sm += __builtin_exp2f(tv[q] - bmx);
      sm = wredSum(sm);
      if (lane == 0) redB[w] = sm;
      __syncthreads();
      if (tid == 0){
        float tot = ((redB[0] + redB[1]) + (redB[2] + redB[3]))
                  + ((redB[4] + redB[5]) + (redB[6] + redB[7]));
        astore(u + r0 + r, lmu[r] - mn - (bmx + __builtin_log2f(tot)) * LN2F);
      }
    }
    gbar3(slots, rel, b, g, ++ep);   // u complete everywhere

    // ---- stage u -> LDS, scaled ----
    {
      float a0 = aload(u + tid);
      float a1 = aload(u + tid + 512);
      ush[tid]       = L2EF * a0;
      ush[tid + 512] = L2EF * a1;
    }
    __syncthreads();

    // ---- v-pass: 4 cols per wave, wave-local reductions; lane owns 4-elem chunks ----
#pragma unroll
    for (int cc = 0; cc < 4; ++cc){
      int j = jc0 + cc;
      const unsigned short* Rc = Mtq + (long)j * MR;
      float tv[16];
      float mx = -INFINITY;
#pragma unroll
      for (int k = 0; k < 4; ++k){
        int i = 4 * lane + 256 * k;
        uint2 q2 = *(const uint2*)(Rc + i);
        float4 uu = *(const float4*)(&ush[i]);
        float e0 = fmaf(s2, (float)(q2.x & 0xFFFFu), uu.x);
        float e1 = fmaf(s2, (float)(q2.x >> 16),     uu.y);
        float e2 = fmaf(s2, (float)(q2.y & 0xFFFFu), uu.z);
        float e3 = fmaf(s2, (float)(q2.y >> 16),     uu.w);
        tv[4*k+0] = e0; tv[4*k+1] = e1; tv[4*k+2] = e2; tv[4*k+3] = e3;
        mx = fmaxf(mx, fmaxf(fmaxf(e0, e1), fmaxf(e2, e3)));
      }
      mx = wredMax(mx);
      float sm = 0.f;
#pragma unroll
      for (int q = 0; q < 16; ++q) sm += __builtin_exp2f(tv[q] - mx);
      sm = wredSum(sm);
      if (lane == 0) astore(v + j, lnu4[cc] - mn - (mx + __builtin_log2f(sm)) * LN2F);
    }
    gbar3(slots, rel, b, g, ++ep);   // v complete everywhere
  }
}

// fallback (R4 path): used only if cooperative launch fails
__global__ __launch_bounds__(256) void kUPassQ(const unsigned short* __restrict__ Mq,
                                               const float* __restrict__ v,
                                               const float* __restrict__ logmu,
                                               float* __restrict__ u,
                                               const float* __restrict__ prm){
  int b = blockIdx.x, tid = threadIdx.x;
  float mn = prm[2], s = prm[3];
  int r0 = 2 * b;
  const unsigned short* R0 = Mq + (long)r0 * NC;
  const unsigned short* R1 = R0 + NC;
  float t0[32], t1[32];
  float mx0 = -INFINITY, mx1 = -INFINITY;
#pragma unroll
  for (int kb = 0; kb < 4; ++kb){
    int cidx = kb * 2048 + tid * 8;
    uint4 qa = *(const uint4*)(R0 + cidx);
    uint4 qb = *(const uint4*)(R1 + cidx);
    float4 v0 = *(const float4*)(v + cidx);
    float4 v1 = *(const float4*)(v + cidx + 4);
    float a0 = fmaf(s, (float)(qa.x & 0xFFFFu), v0.x);
    float a1 = fmaf(s, (float)(qa.x >> 16),     v0.y);
    float a2 = fmaf(s, (float)(qa.y & 0xFFFFu), v0.z);
    float a3 = fmaf(s, (float)(qa.y >> 16),     v0.w);
    float a4 = fmaf(s, (float)(qa.z & 0xFFFFu), v1.x);
    float a5 = fmaf(s, (float)(qa.z >> 16),     v1.y);
    float a6 = fmaf(s, (float)(qa.w & 0xFFFFu), v1.z);
    float a7 = fmaf(s, (float)(qa.w >> 16),     v1.w);
    float c0 = fmaf(s, (float)(qb.x & 0xFFFFu), v0.x);
    float c1 = fmaf(s, (float)(qb.x >> 16),     v0.y);
    float c2 = fmaf(s, (float)(qb.y & 0xFFFFu), v0.z);
    float c3 = fmaf(s, (float)(qb.y >> 16),     v0.w);
    float c4 = fmaf(s, (float)(qb.z & 0xFFFFu), v1.x);
    float c5 = fmaf(s, (float)(qb.z >> 16),     v1.y);
    float c6 = fmaf(s, (float)(qb.w & 0xFFFFu), v1.z);
    float c7 = fmaf(s, (float)(qb.w >> 16),     v1.w);
    t0[kb*8+0]=a0; t0[kb*8+1]=a1; t0[kb*8+2]=a2; t0[kb*8+3]=a3;
    t0[kb*8+4]=a4; t0[kb*8+5]=a5; t0[kb*8+6]=a6; t0[kb*8+7]=a7;
    t1[kb*8+0]=c0; t1[kb*8+1]=c1; t1[kb*8+2]=c2; t1[kb*8+3]=c3;
    t1[kb*8+4]=c4; t1[kb*8+5]=c5; t1[kb*8+6]=c6; t1[kb*8+7]=c7;
    mx0 = fmaxf(mx0, fmaxf(fmaxf(fmaxf(a0,a1),fmaxf(a2,a3)), fmaxf(fmaxf(a4,a5),fmaxf(a6,a7))));
    mx1 = fmaxf(mx1, fmaxf(fmaxf(fmaxf(c0,c1),fmaxf(c2,c3)), fmaxf(fmaxf(c4,c5),fmaxf(c6,c7))));
  }
  __shared__ float redA0[4], redA1[4], redB0[4], redB1[4];
  int lane = tid & 63, w = tid >> 6;
  float wm0 = wredMax(mx0), wm1 = wredMax(mx1);
  if (lane == 0){ redA0[w] = wm0; redA1[w] = wm1; }
  __syncthreads();
  float bm0 = fmaxf(fmaxf(redA0[0], redA0[1]), fmaxf(redA0[2], redA0[3]));
  float bm1 = fmaxf(fmaxf(redA1[0], redA1[1]), fmaxf(redA1[2], redA1[3]));
  float s0 = 0.f, s1 = 0.f;
#pragma unroll
  for (int q = 0; q < 32; ++q){ s0 += __expf(t0[q] - bm0); s1 += __expf(t1[q] - bm1); }
  s0 = wredSum(s0); s1 = wredSum(s1);
  if (lane == 0){ redB0[w] = s0; redB1[w] = s1; }
  __syncthreads();
  if (tid == 0){
    u[r0]     = logmu[r0]     - mn - (bm0 + __logf(redB0[0] + redB0[1] + redB0[2] + redB0[3]));
    u[r0 + 1] = logmu[r0 + 1] - mn - (bm1 + __logf(redB1[0] + redB1[1] + redB1[2] + redB1[3]));
  }
}

__global__ __launch_bounds__(256) void kVPassQ(const unsigned short* __restrict__ Mtq,
                                               const float* __restrict__ u,
                                               const float* __restrict__ lognu,
                                               float* __restrict__ v,
                                               const float* __restrict__ prm){
  __shared__ float ulds[1024];
  int tid = threadIdx.x;
  float mn = prm[2], s = prm[3];
  *(float4*)(&ulds[tid * 4]) = *(const float4*)(u + tid * 4);
  __syncthreads();
  int w = tid >> 6, lane = tid & 63;
#pragma unroll
  for (int cc = 0; cc < 4; ++cc){
    int j = blockIdx.x * 16 + w * 4 + cc;
    const unsigned short* R = Mtq + (long)j * MR;
    float tv[16];
    float mx = -INFINITY;
#pragma unroll
    for (int k = 0; k < 4; ++k){
      int i = 4 * lane + 256 * k;
      uint2 q2 = *(const uint2*)(R + i);
      float4 uu = *(const float4*)(&ulds[i]);
      float e0 = fmaf(s, (float)(q2.x & 0xFFFFu), uu.x);
      float e1 = fmaf(s, (float)(q2.x >> 16),     uu.y);
      float e2 = fmaf(s, (float)(q2.y & 0xFFFFu), uu.z);
      float e3 = fmaf(s, (float)(q2.y >> 16),     uu.w);
      tv[4*k+0] = e0; tv[4*k+1] = e1; tv[4*k+2] = e2; tv[4*k+3] = e3;
      mx = fmaxf(mx, fmaxf(fmaxf(e0, e1), fmaxf(e2, e3)));
    }
    mx = wredMax(mx);
    float sm = 0.f;
#pragma unroll
    for (int q = 0; q < 16; ++q) sm += __expf(tv[q] - mx);
    sm = wredSum(sm);
    if (lane == 0) v[j] = lognu[j] - mn - (mx + __logf(sm));
  }
}

// K5: o = P@T rows, diff = mu*Q - o, acc += sum_i ||diff_i||_2 ; 4 rows per block
__global__ __launch_bounds__(256) void kFinal(const float* __restrict__ x,
                                              const float* __restrict__ att,
                                              const float* __restrict__ M,
                                              const float* __restrict__ u,
                                              const float* __restrict__ v,
                                              float* __restrict__ acc){
  __shared__ float pch[4][256];
  __shared__ float redS[4];
  int tid = threadIdx.x;
  int r0 = blockIdx.x * 4;
  float u4[4];
#pragma unroll
  for (int rr = 0; rr < 4; ++rr) u4[rr] = u[r0 + rr];
  float o[4] = {0.f, 0.f, 0.f, 0.f};
  for (int jc = 0; jc < NC; jc += 256){
    float vv = v[jc + tid];
#pragma unroll
    for (int rr = 0; rr < 4; ++rr)
      pch[rr][tid] = __expf(M[(long)(r0 + rr) * NC + jc + tid] + u4[rr] + vv);
    __syncthreads();
    int k = jc >> 10;
    const float* Tp = x + (1 + k) * IMG_STRIDE + tid * 1024 + (jc & 1023);
    for (int jj = 0; jj < 256; jj += 4){
      float4 tv = *(const float4*)(Tp + jj);
      float tq[4] = {tv.x, tv.y, tv.z, tv.w};
#pragma unroll
      for (int q = 0; q < 4; ++q){
        o[0] += pch[0][jj + q] * tq[q];
        o[1] += pch[1][jj + q] * tq[q];
        o[2] += pch[2][jj + q] * tq[q];
        o[3] += pch[3][jj + q] * tq[q];
      }
    }
    __syncthreads();
  }
  int lane = tid & 63, wid = tid >> 6;
  float dtot = 0.f;
#pragma unroll
  for (int rr = 0; rr < 4; ++rr){
    float mu = att[r0 + rr];
    float qv = x[tid * 1024 + (r0 + rr)];
    float diff = mu * qv - o[rr];
    float wsum = wredSum(diff * diff);
    if (lane == 0) redS[wid] = wsum;
    __syncthreads();
    if (tid == 0) dtot += sqrtf(redS[0] + redS[1] + redS[2] + redS[3]);
    __syncthreads();
  }
  if (tid == 0) atomicAdd(acc, dtot);
}

// K6: apply label/margin, write scalar output
__global__ void kOut(const float* __restrict__ acc, const int* __restrict__ label,
                     float* __restrict__ out){
  if (threadIdx.x == 0 && blockIdx.x == 0){
    float d = *acc;
    out[0] = (*label) ? d : fmaxf(0.7f - d, 0.f);
  }
}

extern "C" void kernel_launch(void* const* d_in, const int* in_sizes, int n_in,
                              void* d_out, int out_size, void* d_ws, size_t ws_size,
                              hipStream_t stream){
  const float* x   = (const float*)d_in[0];
  const float* att = (const float*)d_in[1];
  const int* label = (const int*)d_in[2];
  float* W = (float*)d_ws;
  float* out = (float*)d_out;

  float* M = W;                                                   // 32 MB
  unsigned short* Mq  = (unsigned short*)(W + 8388608);           // 16 MB
  unsigned short* Mtq = (unsigned short*)(W + 8388608 + 4194304); // 16 MB
  float* S     = W + 16777216;
  float* qq    = S;                  // 1024
  float* tt    = S + 1024;           // 8192
  float* logmu = S + 9216;           // 1024
  float* lognu = S + 10240;          // 8192
  float* u     = S + 18432;          // 1024  (16B aligned)
  float* v     = S + 19456;          // 8192  (16B aligned)
  float* acc   = S + 27648;          // 1
  float* prm   = S + 27652;          // 4: [0]=min key, [1]=max key, [2]=mn, [3]=scale
  unsigned* prmI = (unsigned*)prm;
  int*   bar   = (int*)(S + 27664);  // 1024 ints, 16B aligned: [0..255] slots, [256+16g] release

  hipLaunchKernelGGL(kPrep, dim3(37), dim3(256), 0, stream, x, att, qq, tt, logmu, lognu, u, v, acc, prmI, bar);
  hipLaunchKernelGGL(kGemmM, dim3(128, 16), dim3(256), 0, stream, x, qq, tt, M, prmI);
  hipLaunchKernelGGL(kQuantTrans, dim3(128, 16), dim3(256), 0, stream, M, Mq, Mtq, prm);

  void* args[] = { (void*)&Mq, (void*)&Mtq, (void*)&logmu, (void*)&lognu,
                   (void*)&u, (void*)&v, (void*)&prm, (void*)&bar };
  hipError_t rc = hipLaunchCooperativeKernel((const void*)kSink6,
                                             dim3(PBLK), dim3(512), args, 0, stream);
  if (rc != hipSuccess){
    for (int it = 0; it < OT_ITERS; ++it){
      hipLaunchKernelGGL(kUPassQ, dim3(512), dim3(256), 0, stream, Mq, v, logmu, u, prm);
      hipLaunchKernelGGL(kVPassQ, dim3(512), dim3(256), 0, stream, Mtq, u, lognu, v, prm);
    }
  }
  hipLaunchKernelGGL(kFinal, dim3(256), dim3(256), 0, stream, x, att, M, u, v, acc);
  hipLaunchKernelGGL(kOut, dim3(1), dim3(1), 0, stream, acc, label, out);
}

// Round 11
// 12969.202 us; speedup vs baseline: 1.6874x; 1.2761x over previous
//
#include <hip/hip_runtime.h>
#include <math.h>

// Problem constants (fixed by reference: x (9,256,32,32) fp32, att (9,32,32) fp32)
#define MR 1024      // m = 32*32 query locations
#define NC 8192      // n = 8*32*32 target locations
#define NCH 256      // channels
#define OT_ITERS 1000
#define IMG_STRIDE 262144  // 256*1024 floats per image
#define PBLK 512           // persistent grid: 2 blocks/CU (barrier wait overlaps compute)
#define L2EF 1.44269504088896340736f
#define LN2F 0.69314718055994530942f

__device__ inline float wredMax(float v){
#pragma unroll
  for (int m = 32; m >= 1; m >>= 1) v = fmaxf(v, __shfl_xor(v, m, 64));
  return v;
}
__device__ inline float wredMin(float v){
#pragma unroll
  for (int m = 32; m >= 1; m >>= 1) v = fminf(v, __shfl_xor(v, m, 64));
  return v;
}
__device__ inline float wredSum(float v){
#pragma unroll
  for (int m = 32; m >= 1; m >>= 1) v += __shfl_xor(v, m, 64);
  return v;
}

__device__ inline unsigned fkey(float f){
  unsigned b = __float_as_uint(f);
  return (b & 0x80000000u) ? ~b : (b | 0x80000000u);
}
__device__ inline float funkey(unsigned k){
  return (k & 0x80000000u) ? __uint_as_float(k & 0x7fffffffu) : __uint_as_float(~k);
}

// agent-scope (device-coherent) scalar load/store for u/v + barrier exchange
__device__ inline float aload(const float* p){
  return __hip_atomic_load(p, __ATOMIC_RELAXED, __HIP_MEMORY_SCOPE_AGENT);
}
__device__ inline void astore(float* p, float val){
  __hip_atomic_store(p, val, __ATOMIC_RELAXED, __HIP_MEMORY_SCOPE_AGENT);
}

// K1: squared norms, log marginals, zero-init u,v,acc, minmax keys, barrier state
__global__ __launch_bounds__(256) void kPrep(const float* __restrict__ x,
                                             const float* __restrict__ att,
                                             float* __restrict__ qq, float* __restrict__ tt,
                                             float* __restrict__ logmu, float* __restrict__ lognu,
                                             float* __restrict__ u, float* __restrict__ v,
                                             float* __restrict__ acc, unsigned* __restrict__ prmI,
                                             int* __restrict__ bar){
  int idx = blockIdx.x * 256 + threadIdx.x;
  if (idx < 9216){
    int img = idx >> 10, pos = idx & 1023;
    const float* p = x + img * IMG_STRIDE + pos;
    float s = 0.f;
#pragma unroll 8
    for (int c = 0; c < NCH; ++c){ float a = p[c * 1024]; s += a * a; }
    float lg = logf(att[idx]);
    if (img == 0){ qq[idx] = s;        logmu[idx] = lg; }
    else         { tt[idx - 1024] = s; lognu[idx - 1024] = lg; }
  }
  if (idx < MR) u[idx] = 0.f;
  if (idx < NC) v[idx] = 0.f;
  if (idx < 1024) bar[idx] = 0;
  if (idx == 0){ *acc = 0.f; prmI[0] = 0xFFFFFFFFu; prmI[1] = 0u; }
}

// K2: M[i][j] = qq[i] + tt[j] - 2 * Q_i . T_j ; also global min/max via key atomics
__global__ __launch_bounds__(256) void kGemmM(const float* __restrict__ x,
                                              const float* __restrict__ qq,
                                              const float* __restrict__ tt,
                                              float* __restrict__ M,
                                              unsigned* __restrict__ prmI){
  __shared__ float As[16][68];
  __shared__ float Bs[16][68];
  __shared__ float smn[4], smx[4];
  int jb = blockIdx.x;
  int ib = blockIdx.y;
  int i0 = ib * 64;
  int j0 = jb * 64;
  int k  = j0 >> 10, p0 = j0 & 1023;
  const float* A = x + i0;
  const float* B = x + (1 + k) * IMG_STRIDE + p0;
  int tid = threadIdx.x;
  int lr = tid >> 4, lc = (tid & 15) * 4;
  int ty = tid >> 4, tx = tid & 15;
  float accv[4][4] = {};
  for (int kt = 0; kt < 16; ++kt){
    int c = kt * 16 + lr;
    float4 av = *(const float4*)(A + c * 1024 + lc);
    float4 bv = *(const float4*)(B + c * 1024 + lc);
    *(float4*)(&As[lr][lc]) = av;
    *(float4*)(&Bs[lr][lc]) = bv;
    __syncthreads();
#pragma unroll
    for (int kk = 0; kk < 16; ++kk){
      float4 a = *(const float4*)(&As[kk][ty * 4]);
      float4 b = *(const float4*)(&Bs[kk][tx * 4]);
      float ar[4] = {a.x, a.y, a.z, a.w};
      float br[4] = {b.x, b.y, b.z, b.w};
#pragma unroll
      for (int r = 0; r < 4; ++r)
#pragma unroll
        for (int cc = 0; cc < 4; ++cc) accv[r][cc] += ar[r] * br[cc];
    }
    __syncthreads();
  }
  float tmn = INFINITY, tmx = -INFINITY;
#pragma unroll
  for (int r = 0; r < 4; ++r){
    int i = i0 + ty * 4 + r;
    float qi = qq[i];
    float o[4];
#pragma unroll
    for (int cc = 0; cc < 4; ++cc){
      o[cc] = qi + tt[j0 + tx * 4 + cc] - 2.f * accv[r][cc];
      tmn = fminf(tmn, o[cc]); tmx = fmaxf(tmx, o[cc]);
    }
    float4 ov = { o[0], o[1], o[2], o[3] };
    *(float4*)(M + (long)i * NC + j0 + tx * 4) = ov;
  }
  int lane = tid & 63, w = tid >> 6;
  tmn = wredMin(tmn); tmx = wredMax(tmx);
  if (lane == 0){ smn[w] = tmn; smx[w] = tmx; }
  __syncthreads();
  if (tid == 0){
    float bmn = fminf(fminf(smn[0], smn[1]), fminf(smn[2], smn[3]));
    float bmx = fmaxf(fmaxf(smx[0], smx[1]), fmaxf(smx[2], smx[3]));
    atomicMin(&prmI[0], fkey(bmn));
    atomicMax(&prmI[1], fkey(bmx));
  }
}

// K2b: one pass over M -> Mq (u16 row-major) + Mtq (u16 transposed); writes prm scale
__global__ __launch_bounds__(256) void kQuantTrans(const float* __restrict__ M,
                                                   unsigned short* __restrict__ Mq,
                                                   unsigned short* __restrict__ Mtq,
                                                   float* __restrict__ prm){
  __shared__ float tile[64][65];
  const unsigned* prmI = (const unsigned*)prm;
  float mn = funkey(prmI[0]);
  float mx = funkey(prmI[1]);
  float rng = mx - mn;
  float inv = (rng > 0.f) ? 65535.0f / rng : 0.f;
  float sc  = (rng > 0.f) ? rng / 65535.0f : 0.f;
  int i0 = blockIdx.y * 64;
  int j0 = blockIdx.x * 64;
  int t = threadIdx.x;
  int tc = t & 63, tr = t >> 6;
#pragma unroll
  for (int rr = 0; rr < 64; rr += 4)
    tile[rr + tr][tc] = M[(long)(i0 + rr + tr) * NC + j0 + tc];
  __syncthreads();
#pragma unroll
  for (int rr = 0; rr < 64; rr += 4){
    float a = tile[rr + tr][tc];
    int qa = (int)lrintf((a - mn) * inv);
    qa = qa < 0 ? 0 : (qa > 65535 ? 65535 : qa);
    Mq[(long)(i0 + rr + tr) * NC + j0 + tc] = (unsigned short)qa;
    float b = tile[tc][rr + tr];
    int qb = (int)lrintf((b - mn) * inv);
    qb = qb < 0 ? 0 : (qb > 65535 ? 65535 : qb);
    Mtq[(long)(j0 + rr + tr) * MR + i0 + tc] = (unsigned short)qb;
  }
  if (blockIdx.x == 0 && blockIdx.y == 0 && t == 0){ prm[2] = mn; prm[3] = sc; }
}

// hierarchical epoch grid barrier (R6-measured best): 8 groups x 64 blocks;
// relaxed agent RMWs only; per-wave vmcnt drain closes store-visibility window.
__device__ inline void gbar(int* bar, int g, int ep){
  asm volatile("s_waitcnt vmcnt(0)" ::: "memory");  // every wave drains its own stores
  __syncthreads();
  if (threadIdx.x == 0){
    int a = __hip_atomic_fetch_add(&bar[g * 32], 1, __ATOMIC_RELAXED, __HIP_MEMORY_SCOPE_AGENT);
    if (a == 64 * ep - 1){
      int go = __hip_atomic_fetch_add(&bar[512], 1, __ATOMIC_RELAXED, __HIP_MEMORY_SCOPE_AGENT);
      if (go == 8 * ep - 1){
#pragma unroll
        for (int g2 = 0; g2 < 8; ++g2)
          __hip_atomic_store(&bar[256 + g2 * 32], ep, __ATOMIC_RELAXED, __HIP_MEMORY_SCOPE_AGENT);
      }
    }
    while (__hip_atomic_load(&bar[256 + g * 32], __ATOMIC_RELAXED, __HIP_MEMORY_SCOPE_AGENT) < ep)
      __builtin_amdgcn_s_sleep(1);
  }
  __syncthreads();
}

// persistent dense Sinkhorn: 512 blocks x 256 thr; block owns 2 u-rows + 16 v-cols.
// Carried-max single-pass LSE in exp2 domain (exact two-pass fallback it<2 /
// over-underflow). Stride-4 chunks -> conflict-free LDS. u/v via agent scalars.
__global__ __launch_bounds__(256, 2) void kSink7(const unsigned short* __restrict__ Mq,
                                                 const unsigned short* __restrict__ Mtq,
                                                 const float* __restrict__ logmu,
                                                 const float* __restrict__ lognu,
                                                 float* __restrict__ u,
                                                 float* __restrict__ v,
                                                 const float* __restrict__ prm,
                                                 int* __restrict__ bar){
  __shared__ float vsh[8192];   // 32 KB: L2EF * v
  __shared__ float ush[1024];   // 4 KB:  L2EF * u
  __shared__ float redA0[4], redA1[4], redB0[4], redB1[4];
  int tid = threadIdx.x, b = blockIdx.x;
  int lane = tid & 63, w = tid >> 6;
  int g = b & 7;
  float mn = prm[2], s = prm[3];
  float s2 = s * L2EF;
  int r0 = 2 * b;
  const unsigned short* R0 = Mq + (long)r0 * NC;
  const unsigned short* R1 = R0 + NC;
  float lmu0 = logmu[r0], lmu1 = logmu[r0 + 1];
  int jc0 = 16 * b + 4 * w;     // this wave's 4 columns
  float lnu4[4];
#pragma unroll
  for (int cc = 0; cc < 4; ++cc) lnu4[cc] = lognu[jc0 + cc];
  float Bu0 = 0.f, Bu1 = 0.f;   // carried row-LSE (log2 domain)
  float Bv[4] = {0.f, 0.f, 0.f, 0.f};
  int ep = 0;

  for (int it = 0; it < OT_ITERS; ++it){
    // ---- stage v -> LDS (coalesced scalar agent loads), scaled to log2 domain ----
    {
      float tmp[32];
#pragma unroll
      for (int q = 0; q < 32; ++q) tmp[q] = aload(v + tid + 256 * q);
#pragma unroll
      for (int q = 0; q < 32; ++q) vsh[tid + 256 * q] = L2EF * tmp[q];
    }
    __syncthreads();

    // ---- u-pass: 2 rows; thread owns 4-elem chunks j = 4*tid + 1024*k ----
    {
      float Lv0, Lv1;
      bool good = false;
      if (it >= 2){
        float s0 = 0.f, s1 = 0.f;
#pragma unroll
        for (int k = 0; k < 8; ++k){
          int j = 4 * tid + 1024 * k;
          uint2 qa = *(const uint2*)(R0 + j);
          uint2 qb = *(const uint2*)(R1 + j);
          float4 vv = *(const float4*)(&vsh[j]);
          s0 += __builtin_exp2f(fmaf(s2, (float)(qa.x & 0xFFFFu), vv.x) - Bu0)
              + __builtin_exp2f(fmaf(s2, (float)(qa.x >> 16),     vv.y) - Bu0)
              + __builtin_exp2f(fmaf(s2, (float)(qa.y & 0xFFFFu), vv.z) - Bu0)
              + __builtin_exp2f(fmaf(s2, (float)(qa.y >> 16),     vv.w) - Bu0);
          s1 += __builtin_exp2f(fmaf(s2, (float)(qb.x & 0xFFFFu), vv.x) - Bu1)
              + __builtin_exp2f(fmaf(s2, (float)(qb.x >> 16),     vv.y) - Bu1)
              + __builtin_exp2f(fmaf(s2, (float)(qb.y & 0xFFFFu), vv.z) - Bu1)
              + __builtin_exp2f(fmaf(s2, (float)(qb.y >> 16),     vv.w) - Bu1);
        }
        s0 = wredSum(s0); s1 = wredSum(s1);
        if (lane == 0){ redB0[w] = s0; redB1[w] = s1; }
        __syncthreads();
        float tot0 = (redB0[0] + redB0[1]) + (redB0[2] + redB0[3]);
        float tot1 = (redB1[0] + redB1[1]) + (redB1[2] + redB1[3]);
        good = (tot0 > 0.f) && (tot0 < 3.0e38f) && (tot1 > 0.f) && (tot1 < 3.0e38f);
        Lv0 = Bu0 + __builtin_log2f(tot0);
        Lv1 = Bu1 + __builtin_log2f(tot1);
        __syncthreads();
      }
      if (!good){   // exact two-pass (it<2 or guard tripped); block-uniform branch
        float mx0 = -INFINITY, mx1 = -INFINITY;
#pragma unroll
        for (int k = 0; k < 8; ++k){
          int j = 4 * tid + 1024 * k;
          uint2 qa = *(const uint2*)(R0 + j);
          uint2 qb = *(const uint2*)(R1 + j);
          float4 vv = *(const float4*)(&vsh[j]);
          mx0 = fmaxf(mx0, fmaxf(fmaxf(fmaf(s2, (float)(qa.x & 0xFFFFu), vv.x),
                                       fmaf(s2, (float)(qa.x >> 16),     vv.y)),
                                 fmaxf(fmaf(s2, (float)(qa.y & 0xFFFFu), vv.z),
                                       fmaf(s2, (float)(qa.y >> 16),     vv.w))));
          mx1 = fmaxf(mx1, fmaxf(fmaxf(fmaf(s2, (float)(qb.x & 0xFFFFu), vv.x),
                                       fmaf(s2, (float)(qb.x >> 16),     vv.y)),
                                 fmaxf(fmaf(s2, (float)(qb.y & 0xFFFFu), vv.z),
                                       fmaf(s2, (float)(qb.y >> 16),     vv.w))));
        }
        mx0 = wredMax(mx0); mx1 = wredMax(mx1);
        if (lane == 0){ redA0[w] = mx0; redA1[w] = mx1; }
        __syncthreads();
        float bm0 = fmaxf(fmaxf(redA0[0], redA0[1]), fmaxf(redA0[2], redA0[3]));
        float bm1 = fmaxf(fmaxf(redA1[0], redA1[1]), fmaxf(redA1[2], redA1[3]));
        float s0 = 0.f, s1 = 0.f;
#pragma unroll
        for (int k = 0; k < 8; ++k){
          int j = 4 * tid + 1024 * k;
          uint2 qa = *(const uint2*)(R0 + j);
          uint2 qb = *(const uint2*)(R1 + j);
          float4 vv = *(const float4*)(&vsh[j]);
          s0 += __builtin_exp2f(fmaf(s2, (float)(qa.x & 0xFFFFu), vv.x) - bm0)
              + __builtin_exp2f(fmaf(s2, (float)(qa.x >> 16),     vv.y) - bm0)
              + __builtin_exp2f(fmaf(s2, (float)(qa.y & 0xFFFFu), vv.z) - bm0)
              + __builtin_exp2f(fmaf(s2, (float)(qa.y >> 16),     vv.w) - bm0);
          s1 += __builtin_exp2f(fmaf(s2, (float)(qb.x & 0xFFFFu), vv.x) - bm1)
              + __builtin_exp2f(fmaf(s2, (float)(qb.x >> 16),     vv.y) - bm1)
              + __builtin_exp2f(fmaf(s2, (float)(qb.y & 0xFFFFu), vv.z) - bm1)
              + __builtin_exp2f(fmaf(s2, (float)(qb.y >> 16),     vv.w) - bm1);
        }
        s0 = wredSum(s0); s1 = wredSum(s1);
        if (lane == 0){ redB0[w] = s0; redB1[w] = s1; }
        __syncthreads();
        float tot0 = (redB0[0] + redB0[1]) + (redB0[2] + redB0[3]);
        float tot1 = (redB1[0] + redB1[1]) + (redB1[2] + redB1[3]);
        Lv0 = bm0 + __builtin_log2f(tot0);
        Lv1 = bm1 + __builtin_log2f(tot1);
        __syncthreads();
      }
      Bu0 = Lv0; Bu1 = Lv1;
      if (tid == 0){
        astore(u + r0,     lmu0 - mn - Lv0 * LN2F);
        astore(u + r0 + 1, lmu1 - mn - Lv1 * LN2F);
      }
    }
    gbar(bar, g, ++ep);   // u complete everywhere

    // ---- stage u -> LDS, scaled ----
    {
      float tu[4];
#pragma unroll
      for (int q = 0; q < 4; ++q) tu[q] = aload(u + tid + 256 * q);
#pragma unroll
      for (int q = 0; q < 4; ++q) ush[tid + 256 * q] = L2EF * tu[q];
    }
    __syncthreads();

    // ---- v-pass: 4 cols per wave; lane owns 4-elem chunks i = 4*lane + 256*k ----
#pragma unroll
    for (int cc = 0; cc < 4; ++cc){
      int j = jc0 + cc;
      const unsigned short* Rc = Mtq + (long)j * MR;
      float Lv;
      bool good = false;
      if (it >= 2){
        float b2 = Bv[cc];
        float sm = 0.f;
#pragma unroll
        for (int k = 0; k < 4; ++k){
          int i = 4 * lane + 256 * k;
          uint2 q2 = *(const uint2*)(Rc + i);
          float4 uu = *(const float4*)(&ush[i]);
          sm += __builtin_exp2f(fmaf(s2, (float)(q2.x & 0xFFFFu), uu.x) - b2)
              + __builtin_exp2f(fmaf(s2, (float)(q2.x >> 16),     uu.y) - b2)
              + __builtin_exp2f(fmaf(s2, (float)(q2.y & 0xFFFFu), uu.z) - b2)
              + __builtin_exp2f(fmaf(s2, (float)(q2.y >> 16),     uu.w) - b2);
        }
        sm = wredSum(sm);
        good = (sm > 0.f) && (sm < 3.0e38f);
        Lv = b2 + __builtin_log2f(sm);
      }
      if (!good){   // wave-uniform fallback
        float mx = -INFINITY;
#pragma unroll
        for (int k = 0; k < 4; ++k){
          int i = 4 * lane + 256 * k;
          uint2 q2 = *(const uint2*)(Rc + i);
          float4 uu = *(const float4*)(&ush[i]);
          mx = fmaxf(mx, fmaxf(fmaxf(fmaf(s2, (float)(q2.x & 0xFFFFu), uu.x),
                                     fmaf(s2, (float)(q2.x >> 16),     uu.y)),
                               fmaxf(fmaf(s2, (float)(q2.y & 0xFFFFu), uu.z),
                                     fmaf(s2, (float)(q2.y >> 16),     uu.w))));
        }
        mx = wredMax(mx);
        float sm = 0.f;
#pragma unroll
        for (int k = 0; k < 4; ++k){
          int i = 4 * lane + 256 * k;
          uint2 q2 = *(const uint2*)(Rc + i);
          float4 uu = *(const float4*)(&ush[i]);
          sm += __builtin_exp2f(fmaf(s2, (float)(q2.x & 0xFFFFu), uu.x) - mx)
              + __builtin_exp2f(fmaf(s2, (float)(q2.x >> 16),     uu.y) - mx)
              + __builtin_exp2f(fmaf(s2, (float)(q2.y & 0xFFFFu), uu.z) - mx)
              + __builtin_exp2f(fmaf(s2, (float)(q2.y >> 16),     uu.w) - mx);
        }
        sm = wredSum(sm);
        Lv = mx + __builtin_log2f(sm);
      }
      Bv[cc] = Lv;
      if (lane == 0) astore(v + j, lnu4[cc] - mn - Lv * LN2F);
    }
    gbar(bar, g, ++ep);   // v complete everywhere
  }
}

// fallback (R4 path): used only if cooperative launch fails
__global__ __launch_bounds__(256) void kUPassQ(const unsigned short* __restrict__ Mq,
                                               const float* __restrict__ v,
                                               const float* __restrict__ logmu,
                                               float* __restrict__ u,
                                               const float* __restrict__ prm){
  int b = blockIdx.x, tid = threadIdx.x;
  float mn = prm[2], s = prm[3];
  int r0 = 2 * b;
  const unsigned short* R0 = Mq + (long)r0 * NC;
  const unsigned short* R1 = R0 + NC;
  float t0[32], t1[32];
  float mx0 = -INFINITY, mx1 = -INFINITY;
#pragma unroll
  for (int kb = 0; kb < 4; ++kb){
    int cidx = kb * 2048 + tid * 8;
    uint4 qa = *(const uint4*)(R0 + cidx);
    uint4 qb = *(const uint4*)(R1 + cidx);
    float4 v0 = *(const float4*)(v + cidx);
    float4 v1 = *(const float4*)(v + cidx + 4);
    float a0 = fmaf(s, (float)(qa.x & 0xFFFFu), v0.x);
    float a1 = fmaf(s, (float)(qa.x >> 16),     v0.y);
    float a2 = fmaf(s, (float)(qa.y & 0xFFFFu), v0.z);
    float a3 = fmaf(s, (float)(qa.y >> 16),     v0.w);
    float a4 = fmaf(s, (float)(qa.z & 0xFFFFu), v1.x);
    float a5 = fmaf(s, (float)(qa.z >> 16),     v1.y);
    float a6 = fmaf(s, (float)(qa.w & 0xFFFFu), v1.z);
    float a7 = fmaf(s, (float)(qa.w >> 16),     v1.w);
    float c0 = fmaf(s, (float)(qb.x & 0xFFFFu), v0.x);
    float c1 = fmaf(s, (float)(qb.x >> 16),     v0.y);
    float c2 = fmaf(s, (float)(qb.y & 0xFFFFu), v0.z);
    float c3 = fmaf(s, (float)(qb.y >> 16),     v0.w);
    float c4 = fmaf(s, (float)(qb.z & 0xFFFFu), v1.x);
    float c5 = fmaf(s, (float)(qb.z >> 16),     v1.y);
    float c6 = fmaf(s, (float)(qb.w & 0xFFFFu), v1.z);
    float c7 = fmaf(s, (float)(qb.w >> 16),     v1.w);
    t0[kb*8+0]=a0; t0[kb*8+1]=a1; t0[kb*8+2]=a2; t0[kb*8+3]=a3;
    t0[kb*8+4]=a4; t0[kb*8+5]=a5; t0[kb*8+6]=a6; t0[kb*8+7]=a7;
    t1[kb*8+0]=c0; t1[kb*8+1]=c1; t1[kb*8+2]=c2; t1[kb*8+3]=c3;
    t1[kb*8+4]=c4; t1[kb*8+5]=c5; t1[kb*8+6]=c6; t1[kb*8+7]=c7;
    mx0 = fmaxf(mx0, fmaxf(fmaxf(fmaxf(a0,a1),fmaxf(a2,a3)), fmaxf(fmaxf(a4,a5),fmaxf(a6,a7))));
    mx1 = fmaxf(mx1, fmaxf(fmaxf(fmaxf(c0,c1),fmaxf(c2,c3)), fmaxf(fmaxf(c4,c5),fmaxf(c6,c7))));
  }
  __shared__ float redA0[4], redA1[4], redB0[4], redB1[4];
  int lane = tid & 63, w = tid >> 6;
  float wm0 = wredMax(mx0), wm1 = wredMax(mx1);
  if (lane == 0){ redA0[w] = wm0; redA1[w] = wm1; }
  __syncthreads();
  float bm0 = fmaxf(fmaxf(redA0[0], redA0[1]), fmaxf(redA0[2], redA0[3]));
  float bm1 = fmaxf(fmaxf(redA1[0], redA1[1]), fmaxf(redA1[2], redA1[3]));
  float s0 = 0.f, s1 = 0.f;
#pragma unroll
  for (int q = 0; q < 32; ++q){ s0 += __expf(t0[q] - bm0); s1 += __expf(t1[q] - bm1); }
  s0 = wredSum(s0); s1 = wredSum(s1);
  if (lane == 0){ redB0[w] = s0; redB1[w] = s1; }
  __syncthreads();
  if (tid == 0){
    u[r0]     = logmu[r0]     - mn - (bm0 + __logf(redB0[0] + redB0[1] + redB0[2] + redB0[3]));
    u[r0 + 1] = logmu[r0 + 1] - mn - (bm1 + __logf(redB1[0] + redB1[1] + redB1[2] + redB1[3]));
  }
}

__global__ __launch_bounds__(256) void kVPassQ(const unsigned short* __restrict__ Mtq,
                                               const float* __restrict__ u,
                                               const float* __restrict__ lognu,
                                               float* __restrict__ v,
                                               const float* __restrict__ prm){
  __shared__ float ulds[1024];
  int tid = threadIdx.x;
  float mn = prm[2], s = prm[3];
  *(float4*)(&ulds[tid * 4]) = *(const float4*)(u + tid * 4);
  __syncthreads();
  int w = tid >> 6, lane = tid & 63;
#pragma unroll
  for (int cc = 0; cc < 4; ++cc){
    int j = blockIdx.x * 16 + w * 4 + cc;
    const unsigned short* R = Mtq + (long)j * MR;
    float tv[16];
    float mx = -INFINITY;
#pragma unroll
    for (int k = 0; k < 4; ++k){
      int i = 4 * lane + 256 * k;
      uint2 q2 = *(const uint2*)(R + i);
      float4 uu = *(const float4*)(&ulds[i]);
      float e0 = fmaf(s, (float)(q2.x & 0xFFFFu), uu.x);
      float e1 = fmaf(s, (float)(q2.x >> 16),     uu.y);
      float e2 = fmaf(s, (float)(q2.y & 0xFFFFu), uu.z);
      float e3 = fmaf(s, (float)(q2.y >> 16),     uu.w);
      tv[4*k+0] = e0; tv[4*k+1] = e1; tv[4*k+2] = e2; tv[4*k+3] = e3;
      mx = fmaxf(mx, fmaxf(fmaxf(e0, e1), fmaxf(e2, e3)));
    }
    mx = wredMax(mx);
    float sm = 0.f;
#pragma unroll
    for (int q = 0; q < 16; ++q) sm += __expf(tv[q] - mx);
    sm = wredSum(sm);
    if (lane == 0) v[j] = lognu[j] - mn - (mx + __logf(sm));
  }
}

// K5: o = P@T rows, diff = mu*Q - o, acc += sum_i ||diff_i||_2 ; 4 rows per block
__global__ __launch_bounds__(256) void kFinal(const float* __restrict__ x,
                                              const float* __restrict__ att,
                                              const float* __restrict__ M,
                                              const float* __restrict__ u,
                                              const float* __restrict__ v,
                                              float* __restrict__ acc){
  __shared__ float pch[4][256];
  __shared__ float redS[4];
  int tid = threadIdx.x;
  int r0 = blockIdx.x * 4;
  float u4[4];
#pragma unroll
  for (int rr = 0; rr < 4; ++rr) u4[rr] = u[r0 + rr];
  float o[4] = {0.f, 0.f, 0.f, 0.f};
  for (int jc = 0; jc < NC; jc += 256){
    float vv = v[jc + tid];
#pragma unroll
    for (int rr = 0; rr < 4; ++rr)
      pch[rr][tid] = __expf(M[(long)(r0 + rr) * NC + jc + tid] + u4[rr] + vv);
    __syncthreads();
    int k = jc >> 10;
    const float* Tp = x + (1 + k) * IMG_STRIDE + tid * 1024 + (jc & 1023);
    for (int jj = 0; jj < 256; jj += 4){
      float4 tv = *(const float4*)(Tp + jj);
      float tq[4] = {tv.x, tv.y, tv.z, tv.w};
#pragma unroll
      for (int q = 0; q < 4; ++q){
        o[0] += pch[0][jj + q] * tq[q];
        o[1] += pch[1][jj + q] * tq[q];
        o[2] += pch[2][jj + q] * tq[q];
        o[3] += pch[3][jj + q] * tq[q];
      }
    }
    __syncthreads();
  }
  int lane = tid & 63, wid = tid >> 6;
  float dtot = 0.f;
#pragma unroll
  for (int rr = 0; rr < 4; ++rr){
    float mu = att[r0 + rr];
    float qv = x[tid * 1024 + (r0 + rr)];
    float diff = mu * qv - o[rr];
    float wsum = wredSum(diff * diff);
    if (lane == 0) redS[wid] = wsum;
    __syncthreads();
    if (tid == 0) dtot += sqrtf(redS[0] + redS[1] + redS[2] + redS[3]);
    __syncthreads();
  }
  if (tid == 0) atomicAdd(acc, dtot);
}

// K6: apply label/margin, write scalar output
__global__ void kOut(const float* __restrict__ acc, const int* __restrict__ label,
                     float* __restrict__ out){
  if (threadIdx.x == 0 && blockIdx.x == 0){
    float d = *acc;
    out[0] = (*label) ? d : fmaxf(0.7f - d, 0.f);
  }
}

extern "C" void kernel_launch(void* const* d_in, const int* in_sizes, int n_in,
                              void* d_out, int out_size, void* d_ws, size_t ws_size,
                              hipStream_t stream){
  const float* x   = (const float*)d_in[0];
  const float* att = (const float*)d_in[1];
  const int* label = (const int*)d_in[2];
  float* W = (float*)d_ws;
  float* out = (float*)d_out;

  float* M = W;                                                   // 32 MB
  unsigned short* Mq  = (unsigned short*)(W + 8388608);           // 16 MB
  unsigned short* Mtq = (unsigned short*)(W + 8388608 + 4194304); // 16 MB
  float* S     = W + 16777216;
  float* qq    = S;                  // 1024
  float* tt    = S + 1024;           // 8192
  float* logmu = S + 9216;           // 1024
  float* lognu = S + 10240;          // 8192
  float* u     = S + 18432;          // 1024  (16B aligned)
  float* v     = S + 19456;          // 8192  (16B aligned)
  float* acc   = S + 27648;          // 1
  float* prm   = S + 27652;          // 4: [0]=min key, [1]=max key, [2]=mn, [3]=scale
  unsigned* prmI = (unsigned*)prm;
  int*   bar   = (int*)(S + 27664);  // 1024 ints: [g*32] group lines, [512] global, [256+g*32] release

  hipLaunchKernelGGL(kPrep, dim3(37), dim3(256), 0, stream, x, att, qq, tt, logmu, lognu, u, v, acc, prmI, bar);
  hipLaunchKernelGGL(kGemmM, dim3(128, 16), dim3(256), 0, stream, x, qq, tt, M, prmI);
  hipLaunchKernelGGL(kQuantTrans, dim3(128, 16), dim3(256), 0, stream, M, Mq, Mtq, prm);

  void* args[] = { (void*)&Mq, (void*)&Mtq, (void*)&logmu, (void*)&lognu,
                   (void*)&u, (void*)&v, (void*)&prm, (void*)&bar };
  hipError_t rc = hipLaunchCooperativeKernel((const void*)kSink7,
                                             dim3(PBLK), dim3(256), args, 0, stream);
  if (rc != hipSuccess){
    for (int it = 0; it < OT_ITERS; ++it){
      hipLaunchKernelGGL(kUPassQ, dim3(512), dim3(256), 0, stream, Mq, v, logmu, u, prm);
      hipLaunchKernelGGL(kVPassQ, dim3(512), dim3(256), 0, stream, Mtq, u, lognu, v, prm);
    }
  }
  hipLaunchKernelGGL(kFinal, dim3(256), dim3(256), 0, stream, x, att, M, u, v, acc);
  hipLaunchKernelGGL(kOut, dim3(1), dim3(1), 0, stream, acc, label, out);
}